// Round 16
// baseline (714.861 us; speedup 1.0000x reference)
//
#include <hip/hip_runtime.h>
#include <math.h>

#define NROWS 8192
#define DIM   64
#define KSEL  32
#define NQ    (NROWS - KSEL)   /* 8160 query rows */
#define P1LEN 512              /* exact prefix length */
#define CAP   1024             /* per-query candidate list capacity */
#define QTL   128              /* queries per prefix GEMM tile */
#define CTL   128              /* candidates per prefix GEMM tile */
#define CCH   128              /* pass-2 candidates per wave */

// ---------------------------------------------------------------------------
// Kernel A: row norms replicating XLA:CPU (LLVM-vectorized fused reduce):
//   VF=8 lanes, init 0, per-lane FMA chain, horizontal shuffle-tree
//   ((r0+r4)+(r2+r6)) + ((r1+r5)+(r3+r7)).   [validated bit-exact R8-R15]
// ---------------------------------------------------------------------------
__global__ void norms_kernel(const float* __restrict__ x, float* __restrict__ sq) {
    int j = blockIdx.x * blockDim.x + threadIdx.x;
    if (j >= NROWS) return;
    const float* xr = x + (size_t)j * DIM;
    float r[8];
#pragma unroll
    for (int u = 0; u < 8; ++u) r[u] = 0.0f;
#pragma unroll
    for (int i = 0; i < DIM; i += 8) {
#pragma unroll
        for (int u = 0; u < 8; ++u)
            r[u] = __fmaf_rn(xr[i + u], xr[i + u], r[u]);
    }
    const float s04 = __fadd_rn(r[0], r[4]);
    const float s26 = __fadd_rn(r[2], r[6]);
    const float s15 = __fadd_rn(r[1], r[5]);
    const float s37 = __fadd_rn(r[3], r[7]);
    sq[j] = __fadd_rn(__fadd_rn(s04, s26), __fadd_rn(s15, s37));
}

// ---------------------------------------------------------------------------
// Stage a 128-row x 64-dim tile TRANSPOSED into T[k*128 + row].
// ---------------------------------------------------------------------------
__device__ __forceinline__ void stage_tile(const float* __restrict__ x,
                                           int base_row, float* T, int tid) {
    const int row   = tid >> 1;            // 0..127
    const int dbase = (tid & 1) * 32;      // 0 or 32
    const int r     = min(base_row + row, NROWS - 1);
    const float4* src =
        reinterpret_cast<const float4*>(x + (size_t)r * DIM + dbase);
#pragma unroll
    for (int i = 0; i < 8; ++i) {
        float4 v = src[i];
        const int d = dbase + i * 4;
        T[(d + 0) * 128 + row] = v.x;
        T[(d + 1) * 128 + row] = v.y;
        T[(d + 2) * 128 + row] = v.z;
        T[(d + 3) * 128 + row] = v.w;
    }
}

// 8x8 micro-tile k-loop: each acc is a single fp32 FMA chain over k=0..63
// ascending == the validated bit-exact Eigen/XLA dot chain.
#define GEMM_KLOOP(Qs, Cs, acc, tx, ty)                                        \
    _Pragma("unroll 2")                                                        \
    for (int k = 0; k < DIM; ++k) {                                            \
        const float4 q0 = *reinterpret_cast<const float4*>(&Qs[k * 128 + (ty) * 8]);     \
        const float4 q1 = *reinterpret_cast<const float4*>(&Qs[k * 128 + (ty) * 8 + 4]); \
        const float4 c0 = *reinterpret_cast<const float4*>(&Cs[k * 128 + (tx) * 8]);     \
        const float4 c1 = *reinterpret_cast<const float4*>(&Cs[k * 128 + (tx) * 8 + 4]); \
        const float qv[8] = {q0.x, q0.y, q0.z, q0.w, q1.x, q1.y, q1.z, q1.w};  \
        const float cv[8] = {c0.x, c0.y, c0.z, c0.w, c1.x, c1.y, c1.z, c1.w};  \
        _Pragma("unroll")                                                      \
        for (int a = 0; a < 8; ++a)                                            \
            _Pragma("unroll")                                                  \
            for (int b = 0; b < 8; ++b)                                        \
                acc[a][b] = __fmaf_rn(qv[a], cv[b], acc[a][b]);                \
    }

// ---------------------------------------------------------------------------
// Prefix GEMM: all keys for candidates [0, 512) written DIRECT-INDEXED to
// lists[qi][j] (no atomics).  Invalid (j >= r) -> ~0ull.   [validated R15]
// ---------------------------------------------------------------------------
__global__ __launch_bounds__(256)
void prefix_kernel(const float* __restrict__ x, const float* __restrict__ sq,
                   unsigned long long* __restrict__ lists) {
    const int qb = blockIdx.x;             // 0..63
    const int jb = blockIdx.y * CTL;       // 0,128,256,384
    const int Rq = KSEL + qb * QTL;

    __shared__ float Qs[DIM * 128];
    __shared__ float Cs[DIM * 128];
    __shared__ float sqq[QTL], sqc[CTL];

    const int tid = threadIdx.x;
    stage_tile(x, Rq, Qs, tid);
    stage_tile(x, jb, Cs, tid);
    if (tid < QTL) {
        const int rq = Rq + tid;
        sqq[tid] = (rq < NROWS) ? sq[rq] : 0.0f;
    } else {
        sqc[tid - 128] = sq[jb + (tid - 128)];
    }
    __syncthreads();

    const int tx = tid & 15, ty = tid >> 4;
    float acc[8][8] = {{0.f}};
    GEMM_KLOOP(Qs, Cs, acc, tx, ty)

#pragma unroll
    for (int qy = 0; qy < 8; ++qy) {
        const int ql = ty * 8 + qy;
        const int rq = Rq + ql;
        if (rq >= NROWS) continue;
        const int qi = rq - KSEL;
        const float sqr = sqq[ql];
#pragma unroll
        for (int cx = 0; cx < 8; ++cx) {
            const int j = jb + tx * 8 + cx;
            const float dd = fmaxf(
                __fsub_rn(__fadd_rn(sqr, sqc[tx * 8 + cx]),
                          __fmul_rn(2.0f, acc[qy][cx])), 0.0f);
            unsigned long long key =
                ((unsigned long long)__float_as_uint(dd) << 32) | (unsigned)j;
            if (j >= rq) key = ~0ull;
            lists[(size_t)qi * CAP + j] = key;
        }
    }
}

// ---------------------------------------------------------------------------
// Tau-select: ONE WAVE per query.  Coalesced read of the 512 prefix keys,
// 32 shuffle-only extract-min iterations (u64-min = ascending (dist, idx),
// low-index ties).  Writes exact top-32 to lists[qi][0..31], tau0, cnt=32.
// ---------------------------------------------------------------------------
__global__ __launch_bounds__(64)
void tausel_kernel(unsigned long long* __restrict__ lists,
                   unsigned long long* __restrict__ tau0,
                   unsigned int* __restrict__ cnt) {
    const int qi   = blockIdx.x;
    const int lane = threadIdx.x;
    unsigned long long* src = lists + (size_t)qi * CAP;

    unsigned long long k[8];
#pragma unroll
    for (int s = 0; s < 8; ++s) k[s] = src[lane + (s << 6)];

    unsigned long long pmin = ~0ull;
#pragma unroll
    for (int s = 0; s < 8; ++s) pmin = k[s] < pmin ? k[s] : pmin;

    unsigned long long g = ~0ull;
    for (int it = 0; it < KSEL; ++it) {
        unsigned long long v = pmin;
#pragma unroll
        for (int off = 32; off > 0; off >>= 1) {
            const unsigned long long o = __shfl_down(v, off, 64);
            v = o < v ? o : v;
        }
        g = __shfl(v, 0, 64);
        if (lane == 0) src[it] = g;
        if (pmin == g) {
#pragma unroll
            for (int s = 0; s < 8; ++s) if (k[s] == g) k[s] = ~0ull;
            pmin = ~0ull;
#pragma unroll
            for (int s = 0; s < 8; ++s) pmin = k[s] < pmin ? k[s] : pmin;
        }
    }
    if (lane == 0) { tau0[qi] = g; cnt[qi] = KSEL; }
}

// ---------------------------------------------------------------------------
// Pass 2: tail filter, UNIFORM-CANDIDATE structure.  Wave = 64 consecutive
// queries x 128-candidate chunk.  Candidate row is wave-uniform -> compiler
// scalarizes to s_load (SGPRs, scalar pipe); q[64] per-lane in VGPRs.
// ILP-1 candidate loop (ILP>1 triggers spill/hoist pathologies, R12/R13).
// Dot = bit-exact seq-FMA chain k=0..63.  Accept bits(d) <= tau_hi
// (safe superset), append via atomicAdd.  NO LDS.
// ---------------------------------------------------------------------------
__global__ __launch_bounds__(256, 4)
void pass2_kernel(const float* __restrict__ x, const float* __restrict__ sq,
                  const unsigned long long* __restrict__ tau0,
                  unsigned int* __restrict__ cnt,
                  unsigned long long* __restrict__ lists) {
    const int qg   = blockIdx.x;                   // 0..127: query group
    const int wave = threadIdx.x >> 6;
    const int lane = threadIdx.x & 63;
    const int cc   = blockIdx.y * 4 + wave;        // candidate chunk 0..59

    const int r_hi = min(KSEL + (qg + 1) * 64, NROWS);
    const int jbeg = P1LEN + cc * CCH;
    if (jbeg >= r_hi) return;                      // wave-uniform exit, no LDS
    const int jend = min(jbeg + CCH, r_hi);

    const int  r_raw = KSEL + qg * 64 + lane;
    const bool vq    = (r_raw < NROWS);
    const int  r     = vq ? r_raw : 0;             // r=0 => never accepts
    const int  qrow  = vq ? r_raw : 0;
    const int  qi    = vq ? (r_raw - KSEL) : 0;
    const unsigned tau_hi = vq ? (unsigned)(tau0[qi] >> 32) : 0u;

    float q[DIM];                                  // per-lane query in VGPRs
    const float4* q4 = reinterpret_cast<const float4*>(x + (size_t)qrow * DIM);
#pragma unroll
    for (int i = 0; i < DIM / 4; ++i) {
        float4 v = q4[i];
        q[4 * i + 0] = v.x; q[4 * i + 1] = v.y;
        q[4 * i + 2] = v.z; q[4 * i + 3] = v.w;
    }
    const float sqr = vq ? sq[r_raw] : 0.0f;

    for (int j = jbeg; j < jend; ++j) {
        const float* c = x + (size_t)j * DIM;      // uniform -> s_load path
        float a = 0.0f;
#pragma unroll
        for (int d = 0; d < DIM; ++d)              // bit-exact seq chain
            a = __fmaf_rn(q[d], c[d], a);
        const float dd = fmaxf(
            __fsub_rn(__fadd_rn(sqr, sq[j]), __fmul_rn(2.0f, a)), 0.0f);
        const unsigned bits = __float_as_uint(dd);
        if (j < r && bits <= tau_hi) {
            const unsigned s = atomicAdd(&cnt[qi], 1u);
            if (s < CAP)
                lists[(size_t)qi * CAP + s] =
                    ((unsigned long long)bits << 32) | (unsigned)j;
        }
    }
}

// ---------------------------------------------------------------------------
// Merge: ONE WAVE per query.  16 keys/lane in registers, 32 shuffle-only
// extract-min iterations (validated).  List is a superset of true top-32.
// ---------------------------------------------------------------------------
__global__ __launch_bounds__(64)
void merge_kernel(const unsigned long long* __restrict__ lists,
                  const unsigned int* __restrict__ cnt,
                  float* __restrict__ out_d, float* __restrict__ out_i) {
    const int qi   = blockIdx.x;
    const int lane = threadIdx.x;
    const int ne   = min((int)cnt[qi], CAP);
    const unsigned long long* src = lists + (size_t)qi * CAP;

    unsigned long long k[16];
#pragma unroll
    for (int s = 0; s < 16; ++s) {
        const int idx = lane + (s << 6);
        k[s] = (idx < ne) ? src[idx] : ~0ull;
    }
    unsigned long long pmin = ~0ull;
#pragma unroll
    for (int s = 0; s < 16; ++s) pmin = k[s] < pmin ? k[s] : pmin;

    for (int it = 0; it < KSEL; ++it) {
        unsigned long long v = pmin;
#pragma unroll
        for (int off = 32; off > 0; off >>= 1) {
            const unsigned long long o = __shfl_down(v, off, 64);
            v = o < v ? o : v;
        }
        const unsigned long long g = __shfl(v, 0, 64);
        if (lane == 0) {
            out_d[(size_t)qi * KSEL + it] = __uint_as_float((unsigned)(g >> 32));
            out_i[(size_t)qi * KSEL + it] = (float)(unsigned)(g & 0xFFFFFFFFu);
        }
        if (pmin == g) {
#pragma unroll
            for (int s = 0; s < 16; ++s) if (k[s] == g) k[s] = ~0ull;
            pmin = ~0ull;
#pragma unroll
            for (int s = 0; s < 16; ++s) pmin = k[s] < pmin ? k[s] : pmin;
        }
    }
}

extern "C" void kernel_launch(void* const* d_in, const int* in_sizes, int n_in,
                              void* d_out, int out_size, void* d_ws, size_t ws_size,
                              hipStream_t stream) {
    const float* x = (const float*)d_in[0];    // anchor_x [8192, 64] fp32
    float* sq = (float*)d_ws;                                        // 32 KB
    unsigned long long* tau0 =
        (unsigned long long*)((char*)d_ws + 32768);                  // 64 KB
    unsigned int* cnt = (unsigned int*)((char*)d_ws + 98304);        // 32 KB
    unsigned long long* lists =
        (unsigned long long*)((char*)d_ws + 131072);                 // 66.8 MB
    float* out_d = (float*)d_out;              // [8160, 32] distances
    float* out_i = out_d + (size_t)NQ * KSEL;  // [8160, 32] indices (as fp32)

    norms_kernel<<<NROWS / 256, 256, 0, stream>>>(x, sq);
    dim3 gp(64, P1LEN / CTL);                  // prefix: 64 qtiles x 4 ctiles
    prefix_kernel<<<gp, 256, 0, stream>>>(x, sq, lists);
    tausel_kernel<<<NQ, 64, 0, stream>>>(lists, tau0, cnt);
    dim3 g2(128, 15);                          // (query group, 4-chunk block)
    pass2_kernel<<<g2, 256, 0, stream>>>(x, sq, tau0, cnt, lists);
    merge_kernel<<<NQ, 64, 0, stream>>>(lists, cnt, out_d, out_i);
}

// Round 17
// 468.382 us; speedup vs baseline: 1.5262x; 1.5262x over previous
//
#include <hip/hip_runtime.h>
#include <math.h>

#define NROWS 8192
#define DIM   64
#define KSEL  32
#define NQ    (NROWS - KSEL)   /* 8160 query rows */
#define P1LEN 512              /* exact prefix length */
#define CAP   1024             /* per-query candidate list capacity */
#define QTL   128              /* queries per GEMM tile */
#define CTL   128              /* candidates per GEMM tile */

// ---------------------------------------------------------------------------
// Kernel A: row norms replicating XLA:CPU (LLVM-vectorized fused reduce):
//   VF=8 lanes, init 0, per-lane FMA chain, horizontal shuffle-tree
//   ((r0+r4)+(r2+r6)) + ((r1+r5)+(r3+r7)).   [validated bit-exact R8-R16]
// ---------------------------------------------------------------------------
__global__ void norms_kernel(const float* __restrict__ x, float* __restrict__ sq) {
    int j = blockIdx.x * blockDim.x + threadIdx.x;
    if (j >= NROWS) return;
    const float* xr = x + (size_t)j * DIM;
    float r[8];
#pragma unroll
    for (int u = 0; u < 8; ++u) r[u] = 0.0f;
#pragma unroll
    for (int i = 0; i < DIM; i += 8) {
#pragma unroll
        for (int u = 0; u < 8; ++u)
            r[u] = __fmaf_rn(xr[i + u], xr[i + u], r[u]);
    }
    const float s04 = __fadd_rn(r[0], r[4]);
    const float s26 = __fadd_rn(r[2], r[6]);
    const float s15 = __fadd_rn(r[1], r[5]);
    const float s37 = __fadd_rn(r[3], r[7]);
    sq[j] = __fadd_rn(__fadd_rn(s04, s26), __fadd_rn(s15, s37));
}

// ---------------------------------------------------------------------------
// Stage a 128-row x 64-dim tile TRANSPOSED into T[k*128 + row].
// row = tid>>1 -> 32 distinct rows per wave -> 2-way bank aliasing (free).
// ---------------------------------------------------------------------------
__device__ __forceinline__ void stage_tile(const float* __restrict__ x,
                                           int base_row, float* T, int tid) {
    const int row   = tid >> 1;            // 0..127
    const int dbase = (tid & 1) * 32;      // 0 or 32
    const int r     = min(base_row + row, NROWS - 1);
    const float4* src =
        reinterpret_cast<const float4*>(x + (size_t)r * DIM + dbase);
#pragma unroll
    for (int i = 0; i < 8; ++i) {
        float4 v = src[i];
        const int d = dbase + i * 4;
        T[(d + 0) * 128 + row] = v.x;
        T[(d + 1) * 128 + row] = v.y;
        T[(d + 2) * 128 + row] = v.z;
        T[(d + 3) * 128 + row] = v.w;
    }
}

// ---------------------------------------------------------------------------
// Split 8x8 micro-tile k-loop.  Thread (tx,ty) owns queries
// {ty*4..+4} u {64+ty*4..+4} and candidates {tx*4..+4} u {64+tx*4..+4}.
// Reads: Qs broadcast (4 addrs/wave), Cs stride-4 2-way (free) -- NO
// bank conflicts.  Each acc[a][b] = single fp32 FMA chain over k=0..63
// ascending == the validated bit-exact Eigen/XLA dot chain.
// ---------------------------------------------------------------------------
#define GEMM_KLOOP(Qs, Cs, acc, tx, ty)                                        \
    _Pragma("unroll 2")                                                        \
    for (int k = 0; k < DIM; ++k) {                                            \
        const float4 q0 = *reinterpret_cast<const float4*>(&Qs[k * 128 + (ty) * 4]);      \
        const float4 q1 = *reinterpret_cast<const float4*>(&Qs[k * 128 + 64 + (ty) * 4]); \
        const float4 c0 = *reinterpret_cast<const float4*>(&Cs[k * 128 + (tx) * 4]);      \
        const float4 c1 = *reinterpret_cast<const float4*>(&Cs[k * 128 + 64 + (tx) * 4]); \
        const float qv[8] = {q0.x, q0.y, q0.z, q0.w, q1.x, q1.y, q1.z, q1.w};  \
        const float cv[8] = {c0.x, c0.y, c0.z, c0.w, c1.x, c1.y, c1.z, c1.w};  \
        _Pragma("unroll")                                                      \
        for (int a = 0; a < 8; ++a)                                            \
            _Pragma("unroll")                                                  \
            for (int b = 0; b < 8; ++b)                                        \
                acc[a][b] = __fmaf_rn(qv[a], cv[b], acc[a][b]);                \
    }

__device__ __forceinline__ int qlocal(int ty, int a) {
    return (a < 4) ? (ty * 4 + a) : (64 + ty * 4 + (a - 4));
}
__device__ __forceinline__ int clocal(int tx, int b) {
    return (b < 4) ? (tx * 4 + b) : (64 + tx * 4 + (b - 4));
}

// ---------------------------------------------------------------------------
// Prefix GEMM: all keys for candidates [0, 512) written DIRECT-INDEXED to
// lists[qi][j] (no atomics).  Invalid (j >= r) -> ~0ull.   [validated R15]
// ---------------------------------------------------------------------------
__global__ __launch_bounds__(256)
void prefix_kernel(const float* __restrict__ x, const float* __restrict__ sq,
                   unsigned long long* __restrict__ lists) {
    const int qb = blockIdx.x;             // 0..63
    const int jb = blockIdx.y * CTL;       // 0,128,256,384
    const int Rq = KSEL + qb * QTL;

    __shared__ float Qs[DIM * 128];
    __shared__ float Cs[DIM * 128];
    __shared__ float sqq[QTL], sqc[CTL];

    const int tid = threadIdx.x;
    stage_tile(x, Rq, Qs, tid);
    stage_tile(x, jb, Cs, tid);
    if (tid < QTL) {
        const int rq = Rq + tid;
        sqq[tid] = (rq < NROWS) ? sq[rq] : 0.0f;
    } else {
        sqc[tid - 128] = sq[jb + (tid - 128)];
    }
    __syncthreads();

    const int tx = tid & 15, ty = tid >> 4;
    float acc[8][8] = {{0.f}};
    GEMM_KLOOP(Qs, Cs, acc, tx, ty)

#pragma unroll
    for (int a = 0; a < 8; ++a) {
        const int ql = qlocal(ty, a);
        const int rq = Rq + ql;
        if (rq >= NROWS) continue;
        const int qi = rq - KSEL;
        const float sqr = sqq[ql];
#pragma unroll
        for (int b = 0; b < 8; ++b) {
            const int cl = clocal(tx, b);
            const int j = jb + cl;
            const float dd = fmaxf(
                __fsub_rn(__fadd_rn(sqr, sqc[cl]),
                          __fmul_rn(2.0f, acc[a][b])), 0.0f);
            unsigned long long key =
                ((unsigned long long)__float_as_uint(dd) << 32) | (unsigned)j;
            if (j >= rq) key = ~0ull;
            lists[(size_t)qi * CAP + j] = key;
        }
    }
}

// ---------------------------------------------------------------------------
// Tau-select: ONE WAVE per query.  Coalesced read of the 512 prefix keys,
// 32 shuffle-only extract-min iterations (u64-min = ascending (dist, idx),
// low-index ties).  Writes exact top-32 to lists[qi][0..31], tau0, cnt=32.
// ---------------------------------------------------------------------------
__global__ __launch_bounds__(64)
void tausel_kernel(unsigned long long* __restrict__ lists,
                   unsigned long long* __restrict__ tau0,
                   unsigned int* __restrict__ cnt) {
    const int qi   = blockIdx.x;
    const int lane = threadIdx.x;
    unsigned long long* src = lists + (size_t)qi * CAP;

    unsigned long long k[8];
#pragma unroll
    for (int s = 0; s < 8; ++s) k[s] = src[lane + (s << 6)];

    unsigned long long pmin = ~0ull;
#pragma unroll
    for (int s = 0; s < 8; ++s) pmin = k[s] < pmin ? k[s] : pmin;

    unsigned long long g = ~0ull;
    for (int it = 0; it < KSEL; ++it) {
        unsigned long long v = pmin;
#pragma unroll
        for (int off = 32; off > 0; off >>= 1) {
            const unsigned long long o = __shfl_down(v, off, 64);
            v = o < v ? o : v;
        }
        g = __shfl(v, 0, 64);
        if (lane == 0) src[it] = g;
        if (pmin == g) {
#pragma unroll
            for (int s = 0; s < 8; ++s) if (k[s] == g) k[s] = ~0ull;
            pmin = ~0ull;
#pragma unroll
            for (int s = 0; s < 8; ++s) pmin = k[s] < pmin ? k[s] : pmin;
        }
    }
    if (lane == 0) { tau0[qi] = g; cnt[qi] = KSEL; }
}

// ---------------------------------------------------------------------------
// Pass 2: tail GEMM filter over candidates [512, r).  128x128 tile,
// conflict-free split 8x8 micro-tile.  Accept bits(dist) <= tau_hi
// (safe superset: 32nd-of-prefix >= 32nd-overall), append via atomicAdd.
// ---------------------------------------------------------------------------
__global__ __launch_bounds__(256)
void pass2_kernel(const float* __restrict__ x, const float* __restrict__ sq,
                  const unsigned long long* __restrict__ tau0,
                  unsigned int* __restrict__ cnt,
                  unsigned long long* __restrict__ lists) {
    const int qb   = blockIdx.x;                        // 0..63
    const int jb   = P1LEN + blockIdx.y * CTL;          // 512..8064
    const int Rq   = KSEL + qb * QTL;
    const int r_hi = min(Rq + QTL, NROWS);
    if (jb >= r_hi) return;                             // uniform exit

    __shared__ float Qs[DIM * 128];
    __shared__ float Cs[DIM * 128];
    __shared__ float sqq[QTL], sqc[CTL];
    __shared__ unsigned tauh[QTL];

    const int tid = threadIdx.x;
    stage_tile(x, Rq, Qs, tid);
    stage_tile(x, jb, Cs, tid);
    if (tid < QTL) {
        const int rq = Rq + tid;
        const bool v = (rq < NROWS);
        sqq[tid]  = v ? sq[rq] : 0.0f;
        tauh[tid] = v ? (unsigned)(tau0[rq - KSEL] >> 32) : 0u;
    } else {
        sqc[tid - 128] = sq[jb + (tid - 128)];
    }
    __syncthreads();

    const int tx = tid & 15, ty = tid >> 4;
    float acc[8][8] = {{0.f}};
    GEMM_KLOOP(Qs, Cs, acc, tx, ty)

#pragma unroll
    for (int a = 0; a < 8; ++a) {
        const int ql = qlocal(ty, a);
        const int rq = Rq + ql;
        if (rq >= NROWS) continue;
        const int qi = rq - KSEL;
        const float sqr = sqq[ql];
        const unsigned th = tauh[ql];
#pragma unroll
        for (int b = 0; b < 8; ++b) {
            const int cl = clocal(tx, b);
            const int j = jb + cl;
            const float dd = fmaxf(
                __fsub_rn(__fadd_rn(sqr, sqc[cl]),
                          __fmul_rn(2.0f, acc[a][b])), 0.0f);
            const unsigned bits = __float_as_uint(dd);
            if (j < rq && bits <= th) {
                const unsigned s = atomicAdd(&cnt[qi], 1u);
                if (s < CAP)
                    lists[(size_t)qi * CAP + s] =
                        ((unsigned long long)bits << 32) | (unsigned)j;
            }
        }
    }
}

// ---------------------------------------------------------------------------
// Merge: ONE WAVE per query.  16 keys/lane in registers, 32 shuffle-only
// extract-min iterations (validated).  List is a superset of true top-32.
// ---------------------------------------------------------------------------
__global__ __launch_bounds__(64)
void merge_kernel(const unsigned long long* __restrict__ lists,
                  const unsigned int* __restrict__ cnt,
                  float* __restrict__ out_d, float* __restrict__ out_i) {
    const int qi   = blockIdx.x;
    const int lane = threadIdx.x;
    const int ne   = min((int)cnt[qi], CAP);
    const unsigned long long* src = lists + (size_t)qi * CAP;

    unsigned long long k[16];
#pragma unroll
    for (int s = 0; s < 16; ++s) {
        const int idx = lane + (s << 6);
        k[s] = (idx < ne) ? src[idx] : ~0ull;
    }
    unsigned long long pmin = ~0ull;
#pragma unroll
    for (int s = 0; s < 16; ++s) pmin = k[s] < pmin ? k[s] : pmin;

    for (int it = 0; it < KSEL; ++it) {
        unsigned long long v = pmin;
#pragma unroll
        for (int off = 32; off > 0; off >>= 1) {
            const unsigned long long o = __shfl_down(v, off, 64);
            v = o < v ? o : v;
        }
        const unsigned long long g = __shfl(v, 0, 64);
        if (lane == 0) {
            out_d[(size_t)qi * KSEL + it] = __uint_as_float((unsigned)(g >> 32));
            out_i[(size_t)qi * KSEL + it] = (float)(unsigned)(g & 0xFFFFFFFFu);
        }
        if (pmin == g) {
#pragma unroll
            for (int s = 0; s < 16; ++s) if (k[s] == g) k[s] = ~0ull;
            pmin = ~0ull;
#pragma unroll
            for (int s = 0; s < 16; ++s) pmin = k[s] < pmin ? k[s] : pmin;
        }
    }
}

extern "C" void kernel_launch(void* const* d_in, const int* in_sizes, int n_in,
                              void* d_out, int out_size, void* d_ws, size_t ws_size,
                              hipStream_t stream) {
    const float* x = (const float*)d_in[0];    // anchor_x [8192, 64] fp32
    float* sq = (float*)d_ws;                                        // 32 KB
    unsigned long long* tau0 =
        (unsigned long long*)((char*)d_ws + 32768);                  // 64 KB
    unsigned int* cnt = (unsigned int*)((char*)d_ws + 98304);        // 32 KB
    unsigned long long* lists =
        (unsigned long long*)((char*)d_ws + 131072);                 // 66.8 MB
    float* out_d = (float*)d_out;              // [8160, 32] distances
    float* out_i = out_d + (size_t)NQ * KSEL;  // [8160, 32] indices (as fp32)

    norms_kernel<<<NROWS / 256, 256, 0, stream>>>(x, sq);
    dim3 gp(64, P1LEN / CTL);                  // prefix: 64 qtiles x 4 ctiles
    prefix_kernel<<<gp, 256, 0, stream>>>(x, sq, lists);
    tausel_kernel<<<NQ, 64, 0, stream>>>(lists, tau0, cnt);
    dim3 g2(64, (NROWS - P1LEN) / CTL);        // tail: 64 x 60
    pass2_kernel<<<g2, 256, 0, stream>>>(x, sq, tau0, cnt, lists);
    merge_kernel<<<NQ, 64, 0, stream>>>(lists, cnt, out_d, out_i);
}